// Round 10
// baseline (181.721 us; speedup 1.0000x reference)
//
#include <hip/hip_runtime.h>

// DGCNN pipeline R8 — 5 wide launches, balanced:
// L1 k_pre   (3410): gemm1 tiles | per-graph CSR | weff fold
// L2 k_sc1   (1024): scatter1 (graph x col-half), in-place -> xtrain
// L3 k_g2rank(3392): gemm2 tiles | rank blocks (h2[:,63] + argsort + zacc=0)
// L4 k_fin   (1024): scatter2 half + partial folded-MLP -> atomicAdd zacc
// L5 k_sig   (2)   : sigmoid(zacc + beff)

#define NG      512
#define NPG     90
#define EPG     1440
#define IN_DIM  90
#define HD      64
#define KP      70
#define E_TOT   (NG*EPG)

// ws layout (4B element offsets)
#define WEFF_OFF   0                        // 4481 floats
#define EPACK_OFF  4608                     // NG*EPG u32
#define RS_OFF     (EPACK_OFF + NG*EPG)     // NG*96 int
#define D2_OFF     (RS_OFF + NG*96)         // NG*96 float
#define HW2_OFF    (D2_OFF + NG*96)         // 46080*64 float
#define RANK_OFF   (HW2_OFF + 46080*HD)     // NG*72 int
#define ZACC_OFF   (RANK_OFF + NG*72)       // NG float

// ---------------- L1: gemm1 | CSR | weff ----------------
__global__ __launch_bounds__(256) void k_pre(
    const float* __restrict__ x, const int* __restrict__ ei,
    const float* __restrict__ ew, const float* __restrict__ W1,
    const float* __restrict__ lw1, const float* __restrict__ lb1,
    const float* __restrict__ lw2, const float* __restrict__ lb2,
    float* __restrict__ ws, float* __restrict__ xt)
{
    __shared__ float sx[16*IN_DIM];
    __shared__ float s_deg[NPG];
    __shared__ int   s_indeg[NPG];
    __shared__ int   s_rowstart[NPG+1];
    __shared__ int   s_cursor[NPG];

    const int b = blockIdx.x, t = threadIdx.x;

    if (b < 2880) {                       // ---- gemm1 tile: 16 rows ----
        const int row0 = b*16;
        const float4* gx = (const float4*)(x + (size_t)row0*IN_DIM);
        for (int i = t; i < 16*IN_DIM/4; i += 256) ((float4*)sx)[i] = gx[i];
        __syncthreads();
        const int j = t & 63, rg = t >> 6;
        const float2* xp0 = (const float2*)&sx[(rg*4+0)*IN_DIM];
        const float2* xp1 = (const float2*)&sx[(rg*4+1)*IN_DIM];
        const float2* xp2 = (const float2*)&sx[(rg*4+2)*IN_DIM];
        const float2* xp3 = (const float2*)&sx[(rg*4+3)*IN_DIM];
        float a0 = 0.f, a1 = 0.f, a2 = 0.f, a3 = 0.f;
        #pragma unroll 9
        for (int kh = 0; kh < IN_DIM/2; ++kh) {
            float w0 = W1[(2*kh)*HD + j];
            float w1 = W1[(2*kh+1)*HD + j];
            float2 v0 = xp0[kh], v1 = xp1[kh], v2 = xp2[kh], v3 = xp3[kh];
            a0 += v0.x*w0 + v0.y*w1;
            a1 += v1.x*w0 + v1.y*w1;
            a2 += v2.x*w0 + v2.y*w1;
            a3 += v3.x*w0 + v3.y*w1;
        }
        float* o = xt + (size_t)(row0 + rg*4)*HD + j;
        o[0*HD] = a0; o[1*HD] = a1; o[2*HD] = a2; o[3*HD] = a3;
    } else if (b < 3392) {                // ---- CSR build for graph g ----
        const int g = b - 2880;
        const int ebase = g*EPG, nbase = g*NPG;
        if (t < NPG) { s_deg[t] = 1.0f; s_indeg[t] = 0; }
        __syncthreads();
        for (int e = t; e < EPG; e += 256) {
            int d = ei[E_TOT + ebase + e] - nbase;
            atomicAdd(&s_deg[d], ew[ebase + e]);
            atomicAdd(&s_indeg[d], 1);
        }
        __syncthreads();
        if (t < NPG) s_deg[t] = rsqrtf(fmaxf(s_deg[t], 1e-12f));   // dinv
        if (t <= NPG) {
            int acc = 0;
            for (int i = 0; i < t; ++i) acc += s_indeg[i];
            s_rowstart[t] = acc;
            if (t < NPG) s_cursor[t] = acc;
        }
        __syncthreads();
        unsigned* epk = (unsigned*)ws + EPACK_OFF + g*EPG;
        for (int e = t; e < EPG; e += 256) {
            int s = ei[ebase + e] - nbase;
            int d = ei[E_TOT + ebase + e] - nbase;
            float nrm = s_deg[s] * ew[ebase + e] * s_deg[d];
            int pos = atomicAdd(&s_cursor[d], 1);
            epk[pos] = (__float_as_uint(nrm) & ~127u) | (unsigned)s;
        }
        if (t <= NPG) ((int*)ws)[RS_OFF + g*96 + t] = s_rowstart[t];
        if (t < NPG)  ws[D2_OFF + g*96 + t] = s_deg[t]*s_deg[t];
    } else {                              // ---- weff fold ----
        int i = (b-3392)*256 + t;
        if (i < KP*HD) {
            const float4* row = (const float4*)(lw1 + (size_t)i*HD);
            const float4* w   = (const float4*)lw2;
            float s = 0.f;
            #pragma unroll
            for (int j4 = 0; j4 < HD/4; ++j4) {
                float4 r = row[j4], v = w[j4];
                s += r.x*v.x + r.y*v.y + r.z*v.z + r.w*v.w;
            }
            ws[WEFF_OFF + i] = s;
        } else if (i == KP*HD) {
            float s = lb2[0];
            for (int jj = 0; jj < HD; ++jj) s += lb1[jj]*lw2[jj];
            ws[WEFF_OFF + KP*HD] = s;
        }
    }
}

// ---------------- L2: scatter1, graph x col-half, in-place ----------------
__global__ __launch_bounds__(256) void k_sc1(
    float* __restrict__ xt, const float* __restrict__ b1,
    const float* __restrict__ ws)
{
    __shared__ float    sxw[NPG*32];
    __shared__ unsigned sep[EPG];
    __shared__ int      srs[NPG+1];
    __shared__ float    sd2[NPG];

    const int t = threadIdx.x;
    const int g = blockIdx.x >> 1, c0 = (blockIdx.x & 1)*32;
    const int nbase = g*NPG;

    const unsigned* epk = (const unsigned*)ws + EPACK_OFF + g*EPG;
    for (int i = t; i < EPG; i += 256) sep[i] = epk[i];
    if (t <= NPG) srs[t] = ((const int*)ws)[RS_OFF + g*96 + t];
    if (t < NPG)  sd2[t] = ws[D2_OFF + g*96 + t];
    for (int i = t; i < NPG*8; i += 256) {
        int row = i >> 3, f = i & 7;
        ((float4*)sxw)[i] = *(const float4*)(xt + (size_t)(nbase+row)*HD + c0 + f*4);
    }
    __syncthreads();

    for (int o = t; o < NPG*32; o += 256) {
        int d = o >> 5, c = o & 31;
        float a = sd2[d]*sxw[o];
        int p0 = srs[d], p1 = srs[d+1];
        for (int p = p0; p < p1; ++p) {
            unsigned u = sep[p];
            a += __uint_as_float(u & ~127u) * sxw[(int)(u & 127u)*32 + c];
        }
        xt[(size_t)(nbase+d)*HD + c0 + c] = a + b1[c0+c];
    }
}

// ---------------- L3: gemm2 tiles | rank blocks ----------------
__global__ __launch_bounds__(256) void k_g2rank(
    const float* __restrict__ xt, const float* __restrict__ W2,
    const float* __restrict__ b2, float* __restrict__ ws)
{
    __shared__ float    sh[16*HD];         // gemm2 staging
    __shared__ float    sw2c[HD];
    __shared__ float    scol[NPG];
    __shared__ float    h263[NPG];
    __shared__ unsigned sep[EPG];
    __shared__ int      srs[NPG+1];
    __shared__ float    sd2[NPG];
    __shared__ int      srank[KP];

    const int b = blockIdx.x, t = threadIdx.x;

    if (b < 2880) {                       // ---- gemm2 tile: 16 rows ----
        const int row0 = b*16;
        const float4* gh = (const float4*)(xt + (size_t)row0*HD);
        for (int i = t; i < 16*HD/4; i += 256) {
            float4 v = gh[i];
            v.x = fmaxf(v.x, 0.f); v.y = fmaxf(v.y, 0.f);
            v.z = fmaxf(v.z, 0.f); v.w = fmaxf(v.w, 0.f);
            ((float4*)sh)[i] = v;
        }
        __syncthreads();
        const int j = t & 63, rg = t >> 6;
        float a0 = 0.f, a1 = 0.f, a2 = 0.f, a3 = 0.f;
        #pragma unroll 4
        for (int k4 = 0; k4 < HD/4; ++k4) {
            int k = k4*4;
            float4 h0 = *(const float4*)&sh[(rg*4+0)*HD + k];
            float4 h1 = *(const float4*)&sh[(rg*4+1)*HD + k];
            float4 h2 = *(const float4*)&sh[(rg*4+2)*HD + k];
            float4 h3 = *(const float4*)&sh[(rg*4+3)*HD + k];
            float w0 = W2[(k+0)*HD + j];
            float w1 = W2[(k+1)*HD + j];
            float w2 = W2[(k+2)*HD + j];
            float w3 = W2[(k+3)*HD + j];
            a0 += h0.x*w0 + h0.y*w1 + h0.z*w2 + h0.w*w3;
            a1 += h1.x*w0 + h1.y*w1 + h1.z*w2 + h1.w*w3;
            a2 += h2.x*w0 + h2.y*w1 + h2.z*w2 + h2.w*w3;
            a3 += h3.x*w0 + h3.y*w1 + h3.z*w2 + h3.w*w3;
        }
        float* o = ws + HW2_OFF + (size_t)(row0 + rg*4)*HD + j;
        o[0*HD] = a0; o[1*HD] = a1; o[2*HD] = a2; o[3*HD] = a3;
    } else {                              // ---- rank block for graph g ----
        const int g = b - 2880;
        const int nbase = g*NPG;
        if (t < HD) sw2c[t] = W2[t*HD + 63];
        const unsigned* epk = (const unsigned*)ws + EPACK_OFF + g*EPG;
        for (int i = t; i < EPG; i += 256) sep[i] = epk[i];
        if (t <= NPG) srs[t] = ((const int*)ws)[RS_OFF + g*96 + t];
        if (t < NPG)  sd2[t] = ws[D2_OFF + g*96 + t];
        __syncthreads();
        if (t < NPG*4) {                  // hw2 col63: 4 lanes/node
            int n = t >> 2, q = t & 3;
            const float* row = xt + (size_t)(nbase+n)*HD + q*16;
            float s = 0.f;
            #pragma unroll
            for (int k = 0; k < 16; ++k) s += fmaxf(row[k], 0.f)*sw2c[q*16+k];
            s += __shfl_down(s, 2, 4);
            s += __shfl_down(s, 1, 4);
            if (q == 0) scol[n] = s;
        }
        __syncthreads();
        if (t < NPG) {                    // scatter col 63
            float a = sd2[t]*scol[t];
            int p0 = srs[t], p1 = srs[t+1];
            for (int p = p0; p < p1; ++p) {
                unsigned u = sep[p];
                a += __uint_as_float(u & ~127u) * scol[(int)(u & 127u)];
            }
            h263[t] = a + b2[63];
        }
        __syncthreads();
        if (t < NPG) {                    // stable descending rank
            float vi = h263[t];
            int rank = 0;
            for (int jj = 0; jj < NPG; ++jj) {
                float vj = h263[jj];
                rank += (vj > vi) || (vj == vi && jj < t);
            }
            if (rank < KP) srank[rank] = t;
        }
        if (t == 255) ws[ZACC_OFF + g] = 0.f;
        __syncthreads();
        if (t < KP) ((int*)ws)[RANK_OFF + g*72 + t] = srank[t];
    }
}

// ---------------- L4: scatter2 half + partial MLP ----------------
__global__ __launch_bounds__(256) void k_fin(
    const float* __restrict__ b2, float* __restrict__ ws)
{
    __shared__ float    sBh[NPG*32];
    __shared__ float    sCh[NPG*32];
    __shared__ unsigned sep[EPG];
    __shared__ int      srs[NPG+1];
    __shared__ float    sd2[NPG];
    __shared__ int      srank[KP];
    __shared__ float    sred[4];

    const int t = threadIdx.x;
    const int g = blockIdx.x >> 1, c0 = (blockIdx.x & 1)*32;
    const int nbase = g*NPG;
    const int j = t & 63, grp = t >> 6;

    for (int i = t; i < NPG*8; i += 256) {
        int row = i >> 3, f = i & 7;
        ((float4*)sBh)[i] = *(const float4*)(ws + HW2_OFF + (size_t)(nbase+row)*HD + c0 + f*4);
    }
    const unsigned* epk = (const unsigned*)ws + EPACK_OFF + g*EPG;
    for (int i = t; i < EPG; i += 256) sep[i] = epk[i];
    if (t <= NPG) srs[t] = ((const int*)ws)[RS_OFF + g*96 + t];
    if (t < NPG)  sd2[t] = ws[D2_OFF + g*96 + t];
    if (t < KP)   srank[t] = ((const int*)ws)[RANK_OFF + g*72 + t];
    __syncthreads();

    for (int o = t; o < NPG*32; o += 256) {
        int d = o >> 5, c = o & 31;
        float a = sd2[d]*sBh[o];
        int p0 = srs[d], p1 = srs[d+1];
        for (int p = p0; p < p1; ++p) {
            unsigned u = sep[p];
            a += __uint_as_float(u & ~127u) * sBh[(int)(u & 127u)*32 + c];
        }
        sCh[o] = a + b2[c0+c];
    }
    __syncthreads();

    float part = 0.f;
    #pragma unroll
    for (int m = 0; m < 9; ++m) {
        int i = t + m*256;
        if (i < KP*32) {
            int k = i >> 5, c = i & 31;
            part += ws[WEFF_OFF + k*HD + c0 + c] * sCh[srank[k]*32 + c];
        }
    }
    #pragma unroll
    for (int off = 32; off > 0; off >>= 1) part += __shfl_down(part, off, 64);
    if (j == 0) sred[grp] = part;
    __syncthreads();
    if (t == 0) atomicAdd(&ws[ZACC_OFF + g], sred[0]+sred[1]+sred[2]+sred[3]);
}

// ---------------- L5: sigmoid ----------------
__global__ __launch_bounds__(256) void k_sig(
    const float* __restrict__ ws, float* __restrict__ out)
{
    int i = blockIdx.x*256 + threadIdx.x;
    if (i < NG)
        out[i] = 1.0f / (1.0f + expf(-(ws[ZACC_OFF + i] + ws[WEFF_OFF + KP*HD])));
}

extern "C" void kernel_launch(void* const* d_in, const int* in_sizes, int n_in,
                              void* d_out, int out_size, void* d_ws, size_t ws_size,
                              hipStream_t stream) {
    const float* x   = (const float*)d_in[0];
    const int*   ei  = (const int*)  d_in[1];
    const float* ew  = (const float*)d_in[2];
    const float* W1  = (const float*)d_in[4];
    const float* b1  = (const float*)d_in[5];
    const float* W2  = (const float*)d_in[6];
    const float* b2  = (const float*)d_in[7];
    const float* lw1 = (const float*)d_in[8];
    const float* lb1 = (const float*)d_in[9];
    const float* lw2 = (const float*)d_in[10];
    const float* lb2 = (const float*)d_in[11];

    float* ws     = (float*)d_ws;
    float* out    = (float*)d_out;        // [512]
    float* xtrain = out + NG;             // [46080*64]

    k_pre   <<<3410, 256, 0, stream>>>(x, ei, ew, W1, lw1, lb1, lw2, lb2, ws, xtrain);
    k_sc1   <<<1024, 256, 0, stream>>>(xtrain, b1, ws);
    k_g2rank<<<3392, 256, 0, stream>>>(xtrain, W2, b2, ws);
    k_fin   <<<1024, 256, 0, stream>>>(b2, ws);
    k_sig   <<<2,    256, 0, stream>>>(ws, out);
}

// Round 11
// 167.002 us; speedup vs baseline: 1.0881x; 1.0881x over previous
//
#include <hip/hip_runtime.h>

// DGCNN R11 — 2 launches:
// A k_pre   (3410 blk): gemm1 tiles | per-graph CSR | weff fold   (wide)
// D k_graph (512 blk x 512 thr): per graph: stage xw+CSR -> scatter1
//    -> xtrain+relu -> gemm2 -> scatter2 -> rank -> folded MLP -> sigmoid

#define NG      512
#define NPG     90
#define EPG     1440
#define IN_DIM  90
#define HD      64
#define KP      70
#define E_TOT   (NG*EPG)

// ws layout (4B element offsets)
#define WEFF_OFF   0                        // 4481 floats
#define EPACK_OFF  4608                     // NG*EPG u32
#define RS_OFF     (EPACK_OFF + NG*EPG)     // NG*96 int
#define D2_OFF     (RS_OFF + NG*96)         // NG*96 float

// ---------------- A: gemm1 | CSR | weff ----------------
__global__ __launch_bounds__(256) void k_pre(
    const float* __restrict__ x, const int* __restrict__ ei,
    const float* __restrict__ ew, const float* __restrict__ W1,
    const float* __restrict__ lw1, const float* __restrict__ lb1,
    const float* __restrict__ lw2, const float* __restrict__ lb2,
    float* __restrict__ ws, float* __restrict__ xt)
{
    __shared__ float sx[16*IN_DIM];
    __shared__ float s_deg[NPG];
    __shared__ int   s_indeg[NPG];
    __shared__ int   s_rowstart[NPG+1];
    __shared__ int   s_cursor[NPG];

    const int b = blockIdx.x, t = threadIdx.x;

    if (b < 2880) {                       // ---- gemm1 tile: 16 rows ----
        const int row0 = b*16;
        const float4* gx = (const float4*)(x + (size_t)row0*IN_DIM);
        for (int i = t; i < 16*IN_DIM/4; i += 256) ((float4*)sx)[i] = gx[i];
        __syncthreads();
        const int j = t & 63, rg = t >> 6;
        const float2* xp0 = (const float2*)&sx[(rg*4+0)*IN_DIM];
        const float2* xp1 = (const float2*)&sx[(rg*4+1)*IN_DIM];
        const float2* xp2 = (const float2*)&sx[(rg*4+2)*IN_DIM];
        const float2* xp3 = (const float2*)&sx[(rg*4+3)*IN_DIM];
        float a0 = 0.f, a1 = 0.f, a2 = 0.f, a3 = 0.f;
        #pragma unroll 9
        for (int kh = 0; kh < IN_DIM/2; ++kh) {
            float w0 = W1[(2*kh)*HD + j];
            float w1 = W1[(2*kh+1)*HD + j];
            float2 v0 = xp0[kh], v1 = xp1[kh], v2 = xp2[kh], v3 = xp3[kh];
            a0 += v0.x*w0 + v0.y*w1;
            a1 += v1.x*w0 + v1.y*w1;
            a2 += v2.x*w0 + v2.y*w1;
            a3 += v3.x*w0 + v3.y*w1;
        }
        float* o = xt + (size_t)(row0 + rg*4)*HD + j;
        o[0*HD] = a0; o[1*HD] = a1; o[2*HD] = a2; o[3*HD] = a3;
    } else if (b < 3392) {                // ---- CSR build for graph g ----
        const int g = b - 2880;
        const int ebase = g*EPG, nbase = g*NPG;
        if (t < NPG) { s_deg[t] = 1.0f; s_indeg[t] = 0; }
        __syncthreads();
        for (int e = t; e < EPG; e += 256) {
            int d = ei[E_TOT + ebase + e] - nbase;
            atomicAdd(&s_deg[d], ew[ebase + e]);
            atomicAdd(&s_indeg[d], 1);
        }
        __syncthreads();
        if (t < NPG) s_deg[t] = rsqrtf(fmaxf(s_deg[t], 1e-12f));   // dinv
        if (t <= NPG) {
            int acc = 0;
            for (int i = 0; i < t; ++i) acc += s_indeg[i];
            s_rowstart[t] = acc;
            if (t < NPG) s_cursor[t] = acc;
        }
        __syncthreads();
        unsigned* epk = (unsigned*)ws + EPACK_OFF + g*EPG;
        for (int e = t; e < EPG; e += 256) {
            int s = ei[ebase + e] - nbase;
            int d = ei[E_TOT + ebase + e] - nbase;
            float nrm = s_deg[s] * ew[ebase + e] * s_deg[d];
            int pos = atomicAdd(&s_cursor[d], 1);
            epk[pos] = (__float_as_uint(nrm) & ~127u) | (unsigned)s;
        }
        if (t <= NPG) ((int*)ws)[RS_OFF + g*96 + t] = s_rowstart[t];
        if (t < NPG)  ws[D2_OFF + g*96 + t] = s_deg[t]*s_deg[t];
    } else {                              // ---- weff fold ----
        int i = (b-3392)*256 + t;
        if (i < KP*HD) {
            const float4* row = (const float4*)(lw1 + (size_t)i*HD);
            const float4* w   = (const float4*)lw2;
            float s = 0.f;
            #pragma unroll
            for (int j4 = 0; j4 < HD/4; ++j4) {
                float4 r = row[j4], v = w[j4];
                s += r.x*v.x + r.y*v.y + r.z*v.z + r.w*v.w;
            }
            ws[WEFF_OFF + i] = s;
        } else if (i == KP*HD) {
            float s = lb2[0];
            for (int jj = 0; jj < HD; ++jj) s += lb1[jj]*lw2[jj];
            ws[WEFF_OFF + KP*HD] = s;
        }
    }
}

// ---------------- D: per-graph tail (scatter1..sigmoid) ----------------
__global__ __launch_bounds__(512, 4) void k_graph(
    const float* __restrict__ b1, const float* __restrict__ W2,
    const float* __restrict__ b2, const float* __restrict__ ws,
    float* __restrict__ out, float* __restrict__ xt)
{
    __shared__ float    sB[NPG*HD];        // xw -> hw2
    __shared__ float    sC[NPG*HD];        // h1(relu) -> h2
    __shared__ unsigned sep[EPG];
    __shared__ int      srs[NPG+1];
    __shared__ float    sd2[NPG];
    __shared__ int      srank[KP];
    __shared__ float    sred[8];

    const int g = blockIdx.x, t = threadIdx.x;
    const int j = t & 63, grp = t >> 6;
    const int nbase = g*NPG;

    // ---- stage xw + CSR ----
    const float4* gxw = (const float4*)(xt + (size_t)nbase*HD);
    for (int i = t; i < NPG*HD/4; i += 512) ((float4*)sB)[i] = gxw[i];
    const unsigned* epk = (const unsigned*)ws + EPACK_OFF + g*EPG;
    for (int i = t; i < EPG; i += 512) sep[i] = epk[i];
    if (t <= NPG) srs[t] = ((const int*)ws)[RS_OFF + g*96 + t];
    if (t < NPG)  sd2[t] = ws[D2_OFF + g*96 + t];
    __syncthreads();

    // ---- scatter1 + b1 + xtrain store + relu -> sC ----
    float* xtg = xt + (size_t)nbase*HD;
    for (int o = t; o < NPG*HD; o += 512) {
        int d = o >> 6, c = o & 63;
        float a = sd2[d]*sB[o];
        int p0 = srs[d], p1 = srs[d+1];
        for (int p = p0; p < p1; ++p) {
            unsigned u = sep[p];
            a += __uint_as_float(u & ~127u) * sB[(int)(u & 127u)*HD + c];
        }
        a += b1[c];
        xtg[o] = a;
        sC[o] = fmaxf(a, 0.f);
    }
    __syncthreads();

    // ---- gemm2: sB = relu(h1) @ W2 (W2 from global, L1-hot) ----
    for (int it = 0; it < 3; ++it) {
        int r0 = it*32 + grp*4;
        int rr0 = min(r0+0, NPG-1), rr1 = min(r0+1, NPG-1);
        int rr2 = min(r0+2, NPG-1), rr3 = min(r0+3, NPG-1);
        float a0 = 0.f, a1 = 0.f, a2 = 0.f, a3 = 0.f;
        #pragma unroll 4
        for (int k4 = 0; k4 < HD/4; ++k4) {
            int k = k4*4;
            float4 h0 = *(const float4*)&sC[rr0*HD + k];
            float4 h1 = *(const float4*)&sC[rr1*HD + k];
            float4 h2 = *(const float4*)&sC[rr2*HD + k];
            float4 h3 = *(const float4*)&sC[rr3*HD + k];
            float w0 = W2[(k+0)*HD + j];
            float w1 = W2[(k+1)*HD + j];
            float w2 = W2[(k+2)*HD + j];
            float w3 = W2[(k+3)*HD + j];
            a0 += h0.x*w0 + h0.y*w1 + h0.z*w2 + h0.w*w3;
            a1 += h1.x*w0 + h1.y*w1 + h1.z*w2 + h1.w*w3;
            a2 += h2.x*w0 + h2.y*w1 + h2.z*w2 + h2.w*w3;
            a3 += h3.x*w0 + h3.y*w1 + h3.z*w2 + h3.w*w3;
        }
        __syncthreads();                   // sC reads done before sB overwrite?
        if (r0+0 < NPG) sB[(r0+0)*HD + j] = a0;
        if (r0+1 < NPG) sB[(r0+1)*HD + j] = a1;
        if (r0+2 < NPG) sB[(r0+2)*HD + j] = a2;
        if (r0+3 < NPG) sB[(r0+3)*HD + j] = a3;
    }
    __syncthreads();

    // ---- scatter2 -> sC = A_hat @ hw2 + b2 ----
    for (int o = t; o < NPG*HD; o += 512) {
        int d = o >> 6, c = o & 63;
        float a = sd2[d]*sB[o];
        int p0 = srs[d], p1 = srs[d+1];
        for (int p = p0; p < p1; ++p) {
            unsigned u = sep[p];
            a += __uint_as_float(u & ~127u) * sB[(int)(u & 127u)*HD + c];
        }
        sC[o] = a + b2[c];
    }
    __syncthreads();

    // ---- sort-pool rank (stable descending on channel 63) ----
    if (t < NPG) {
        float vi = sC[t*HD + (HD-1)];
        int rank = 0;
        for (int jj = 0; jj < NPG; ++jj) {
            float vj = sC[jj*HD + (HD-1)];
            rank += (vj > vi) || (vj == vi && jj < t);
        }
        if (rank < KP) srank[rank] = t;
    }
    __syncthreads();

    // ---- folded MLP + sigmoid ----
    float part = 0.f;
    #pragma unroll
    for (int m = 0; m < 9; ++m) {
        int i = t + m*512;
        if (i < KP*HD) {
            int k = i >> 6, c = i & 63;               // k uniform per 64-lane group
            part += ws[WEFF_OFF + i] * sC[srank[k]*HD + c];
        }
    }
    #pragma unroll
    for (int off = 32; off > 0; off >>= 1) part += __shfl_down(part, off, 64);
    if (j == 0) sred[grp] = part;
    __syncthreads();
    if (t == 0) {
        float zz = ws[WEFF_OFF + KP*HD];
        #pragma unroll
        for (int m = 0; m < 8; ++m) zz += sred[m];
        out[g] = 1.0f / (1.0f + expf(-zz));
    }
}

extern "C" void kernel_launch(void* const* d_in, const int* in_sizes, int n_in,
                              void* d_out, int out_size, void* d_ws, size_t ws_size,
                              hipStream_t stream) {
    const float* x   = (const float*)d_in[0];
    const int*   ei  = (const int*)  d_in[1];
    const float* ew  = (const float*)d_in[2];
    const float* W1  = (const float*)d_in[4];
    const float* b1  = (const float*)d_in[5];
    const float* W2  = (const float*)d_in[6];
    const float* b2  = (const float*)d_in[7];
    const float* lw1 = (const float*)d_in[8];
    const float* lb1 = (const float*)d_in[9];
    const float* lw2 = (const float*)d_in[10];
    const float* lb2 = (const float*)d_in[11];

    float* ws     = (float*)d_ws;
    float* out    = (float*)d_out;        // [512]
    float* xtrain = out + NG;             // [46080*64]

    k_pre  <<<3410, 256, 0, stream>>>(x, ei, ew, W1, lw1, lb1, lw2, lb2, ws, xtrain);
    k_graph<<<NG,   512, 0, stream>>>(b1, W2, b2, ws, out, xtrain);
}